// Round 6
// baseline (254.276 us; speedup 1.0000x reference)
//
#include <hip/hip_runtime.h>
#include <hip/hip_bf16.h>

typedef __attribute__((ext_vector_type(8))) short short8;
typedef __attribute__((ext_vector_type(4))) float f32x4;
typedef __attribute__((ext_vector_type(4))) uint uint4e;

__device__ __forceinline__ ushort bf16_bits(float v) {
    __hip_bfloat16 h = __float2bfloat16(v);
    return *reinterpret_cast<ushort*>(&h);
}
__device__ __forceinline__ float bf16_val(float v) {
    __hip_bfloat16 h = __float2bfloat16(v);
    return __bfloat162float(h);
}
__device__ __forceinline__ float bfu_lo(uint u) {
    uint t = u << 16; return __uint_as_float(t);
}
__device__ __forceinline__ float bfu_hi(uint u) {
    uint t = u & 0xffff0000u; return __uint_as_float(t);
}

// forced async global load: compiler cannot sink/elide asm volatile, must keep
// dst live -> real prefetch depth (C++ prefetch was re-sunk to JIT, r5: VGPR 64).
__device__ __forceinline__ void gload16(uint4e& d, const ushort* p) {
    asm volatile("global_load_dwordx4 %0, %1, off"
                 : "=&v"(d) : "v"(p) : "memory");
}

// ---------------- CSR build (count-free: degrees computed in binB) ----------------

__global__ __launch_bounds__(256) void k_bcount(const int* __restrict__ col,
                                                int* __restrict__ bcnt, int E) {
    __shared__ int hist[196];
    int tid = threadIdx.x;
    int base = blockIdx.x * 2048;
    if (tid < 196) hist[tid] = 0;
    __syncthreads();
    #pragma unroll
    for (int i = 0; i < 8; i++) {
        int e = base + i * 256 + tid;
        if (e < E) atomicAdd(&hist[col[e] >> 8], 1);
    }
    __syncthreads();
    if (tid < 196 && hist[tid] > 0) atomicAdd(&bcnt[tid], hist[tid]);
}

__global__ __launch_bounds__(256) void k_bscan(const int* __restrict__ bcnt,
                                               int* __restrict__ bbase,
                                               int* __restrict__ bcur, int E) {
    int i = threadIdx.x;
    int v = (i < 196) ? bcnt[i] : 0;
    int lane = i & 63, w = i >> 6;
    int s = v;
    #pragma unroll
    for (int o = 1; o < 64; o <<= 1) {
        int t = __shfl_up(s, o);
        if (lane >= o) s += t;
    }
    __shared__ int wsum[4];
    if (lane == 63) wsum[w] = s;
    __syncthreads();
    int add = 0;
    for (int ww = 0; ww < w; ww++) add += wsum[ww];
    int excl = s + add - v;
    if (i < 196) {
        bbase[i] = excl;
        bcur[i] = excl;
    }
    if (i == 195) bbase[196] = excl + v;   // == E
}

__global__ __launch_bounds__(256) void k_binA(const int* __restrict__ row,
                                              const int* __restrict__ col,
                                              int* __restrict__ bcur,
                                              uint* __restrict__ stage, int E) {
    __shared__ uint colbuf[2048];
    __shared__ int hist[196];
    __shared__ int lcur[196];
    int tid = threadIdx.x;
    int base = blockIdx.x * 2048;
    if (tid < 196) hist[tid] = 0;
    __syncthreads();
    #pragma unroll
    for (int i = 0; i < 8; i++) {
        int e = base + i * 256 + tid;
        uint c = 0xFFFFFFFFu;
        if (e < E) {
            c = (uint)col[e];
            atomicAdd(&hist[c >> 8], 1);
        }
        colbuf[i * 256 + tid] = c;
    }
    __syncthreads();
    if (tid < 196 && hist[tid] > 0) lcur[tid] = atomicAdd(&bcur[tid], hist[tid]);
    __syncthreads();
    #pragma unroll
    for (int i = 0; i < 8; i++) {
        int idx = i * 256 + tid;
        uint c = colbuf[idx];
        if (c != 0xFFFFFFFFu) {
            uint r = (uint)row[base + idx];
            int p = atomicAdd(&lcur[c >> 8], 1);
            stage[p] = (c << 16) | r;
        }
    }
}

__global__ __launch_bounds__(256) void k_binB(const uint* __restrict__ stage,
                                              const int* __restrict__ bbase,
                                              int* __restrict__ rowptr,
                                              float* __restrict__ dis,
                                              ushort* __restrict__ csr16,
                                              int n, int E) {
    __shared__ int cnt[256];
    __shared__ int cur[256];
    __shared__ int wsum[4];
    int b = blockIdx.x;
    int lo = b << 8;
    int tid = threadIdx.x;
    int gstart = bbase[b], gend = bbase[b + 1];
    cnt[tid] = 0;
    __syncthreads();
    for (int idx = gstart + tid; idx < gend; idx += 256)
        atomicAdd(&cnt[(stage[idx] >> 16) & 255], 1);
    __syncthreads();
    int v = cnt[tid];
    int lane = tid & 63, w = tid >> 6;
    int s = v;
    #pragma unroll
    for (int o = 1; o < 64; o <<= 1) {
        int t = __shfl_up(s, o);
        if (lane >= o) s += t;
    }
    if (lane == 63) wsum[w] = s;
    __syncthreads();
    int add = 0;
    for (int ww = 0; ww < w; ww++) add += wsum[ww];
    int excl = s + add - v + gstart;
    int node = lo + tid;
    if (node < n) {
        rowptr[node] = excl;
        dis[node] = v > 0 ? rsqrtf((float)v) : 0.f;
    }
    cur[tid] = excl;
    if (tid == 0 && b == gridDim.x - 1) rowptr[n] = E;
    __syncthreads();
    for (int idx = gstart + tid; idx < gend; idx += 256) {
        uint pk = stage[idx];
        int p = atomicAdd(&cur[(pk >> 16) & 255], 1);
        csr16[p] = (ushort)(pk & 0xffffu);
    }
}

// ---------------- input split: x -> bf16 + dis-scaled bf16 copy ----------------

__global__ __launch_bounds__(256) void k_prepX(const float* __restrict__ x,
                                               const float* __restrict__ dis,
                                               ushort* __restrict__ xh,
                                               ushort* __restrict__ xs, int total4) {
    int i = blockIdx.x * 256 + threadIdx.x;
    if (i >= total4) return;
    float4 v = reinterpret_cast<const float4*>(x)[i];
    float dn = dis[i >> 4];                  // node = (i*4)/64
    float vv[4] = {v.x, v.y, v.z, v.w};
    uint hv[2], sv[2];
    #pragma unroll
    for (int g = 0; g < 2; g++) {
        float a0 = vv[g * 2], a1 = vv[g * 2 + 1];
        hv[g] = (uint)bf16_bits(a0) | ((uint)bf16_bits(a1) << 16);
        sv[g] = (uint)bf16_bits(a0 * dn) | ((uint)bf16_bits(a1 * dn) << 16);
    }
    reinterpret_cast<uint2*>(xh)[i] = make_uint2(hv[0], hv[1]);
    reinterpret_cast<uint2*>(xs)[i] = make_uint2(sv[0], sv[1]);
}

// ---------------- CSR aggregations (gather, no atomics) ----------------

// agg[i] = dis[i] * sum_e xs[row_e], wide-granule: lane = sub(0..7)*8+li(0..7);
// uint4/lane -> 8 rows (1KB) per instruction. Output single bf16 (hi only).
__global__ __launch_bounds__(256) void k_agg64_csr(const ushort* __restrict__ xs,
                                                   const int* __restrict__ rowptr,
                                                   const ushort* __restrict__ csr16,
                                                   const float* __restrict__ dis,
                                                   ushort* __restrict__ agghi, int n) {
    int node = blockIdx.x * 4 + (threadIdx.x >> 6);
    if (node >= n) return;
    int lane = threadIdx.x & 63;
    int sub = lane >> 3;          // edge slot 0..7
    int li  = lane & 7;           // dim group: dims li*8 .. li*8+7
    int s = rowptr[node], t = rowptr[node + 1];
    float acc[8] = {};
    int p = s;
    for (; p + 16 <= t; p += 16) {
        int rr[2];
        #pragma unroll
        for (int u = 0; u < 2; u++) rr[u] = csr16[p + u * 8 + sub];
        uint4 v[2];
        #pragma unroll
        for (int u = 0; u < 2; u++)
            v[u] = *reinterpret_cast<const uint4*>(&xs[(size_t)rr[u] * 64 + li * 8]);
        #pragma unroll
        for (int u = 0; u < 2; u++) {
            acc[0] += bfu_lo(v[u].x); acc[1] += bfu_hi(v[u].x);
            acc[2] += bfu_lo(v[u].y); acc[3] += bfu_hi(v[u].y);
            acc[4] += bfu_lo(v[u].z); acc[5] += bfu_hi(v[u].z);
            acc[6] += bfu_lo(v[u].w); acc[7] += bfu_hi(v[u].w);
        }
    }
    for (; p < t; p += 8) {
        int e = p + sub;
        if (e < t) {
            int rr = csr16[e];
            uint4 v = *reinterpret_cast<const uint4*>(&xs[(size_t)rr * 64 + li * 8]);
            acc[0] += bfu_lo(v.x); acc[1] += bfu_hi(v.x);
            acc[2] += bfu_lo(v.y); acc[3] += bfu_hi(v.y);
            acc[4] += bfu_lo(v.z); acc[5] += bfu_hi(v.z);
            acc[6] += bfu_lo(v.w); acc[7] += bfu_hi(v.w);
        }
    }
    #pragma unroll
    for (int j = 0; j < 8; j++) {
        acc[j] += __shfl_xor(acc[j], 8);
        acc[j] += __shfl_xor(acc[j], 16);
        acc[j] += __shfl_xor(acc[j], 32);
    }
    if (sub == 0) {
        float dn = dis[node];
        uint hp[4];
        #pragma unroll
        for (int g = 0; g < 4; g++) {
            float a0 = acc[g * 2] * dn, a1 = acc[g * 2 + 1] * dn;
            hp[g] = (uint)bf16_bits(a0) | ((uint)bf16_bits(a1) << 16);
        }
        *reinterpret_cast<uint4*>(&agghi[(size_t)node * 64 + li * 8]) =
            make_uint4(hp[0], hp[1], hp[2], hp[3]);
    }
}

// Fused x7 + dual dot, wide-granule gather: lane = sub(0..3)*16 + li(0..15);
// uint4/lane -> 4 rows (1KB) per instruction. x5 is packed bf16.
__global__ __launch_bounds__(256) void k_agg128_x7dot(
    const ushort* __restrict__ xw,
    const int* __restrict__ rowptr,
    const ushort* __restrict__ csr16,
    const float* __restrict__ dis,
    const float* __restrict__ b2,
    const ushort* __restrict__ x5,
    const float* __restrict__ wfc2, const float* __restrict__ bfc2,
    const float* __restrict__ wc3,  const float* __restrict__ bc3,
    float* __restrict__ out, float* __restrict__ xw3, int n) {
    int node = blockIdx.x * 4 + (threadIdx.x >> 6);
    if (node >= n) return;
    int lane = threadIdx.x & 63;
    int sub = lane >> 4;          // edge slot 0..3
    int li  = lane & 15;          // dim group: dims li*8 .. li*8+7
    int s = rowptr[node], t = rowptr[node + 1];
    float acc[8] = {};
    int p = s;
    for (; p + 16 <= t; p += 16) {
        int rr[4];
        #pragma unroll
        for (int u = 0; u < 4; u++) rr[u] = csr16[p + u * 4 + sub];
        uint4 v[4];
        #pragma unroll
        for (int u = 0; u < 4; u++)
            v[u] = *reinterpret_cast<const uint4*>(&xw[(size_t)rr[u] * 128 + li * 8]);
        #pragma unroll
        for (int u = 0; u < 4; u++) {
            acc[0] += bfu_lo(v[u].x); acc[1] += bfu_hi(v[u].x);
            acc[2] += bfu_lo(v[u].y); acc[3] += bfu_hi(v[u].y);
            acc[4] += bfu_lo(v[u].z); acc[5] += bfu_hi(v[u].z);
            acc[6] += bfu_lo(v[u].w); acc[7] += bfu_hi(v[u].w);
        }
    }
    for (; p < t; p += 4) {
        int e = p + sub;
        if (e < t) {
            int rr = csr16[e];
            uint4 v = *reinterpret_cast<const uint4*>(&xw[(size_t)rr * 128 + li * 8]);
            acc[0] += bfu_lo(v.x); acc[1] += bfu_hi(v.x);
            acc[2] += bfu_lo(v.y); acc[3] += bfu_hi(v.y);
            acc[4] += bfu_lo(v.z); acc[5] += bfu_hi(v.z);
            acc[6] += bfu_lo(v.w); acc[7] += bfu_hi(v.w);
        }
    }
    #pragma unroll
    for (int j = 0; j < 8; j++) {
        acc[j] += __shfl_xor(acc[j], 16);
        acc[j] += __shfl_xor(acc[j], 32);
    }
    float dn = dis[node];
    float s1 = 0.f, s2 = 0.f;
    if (sub == 0) {
        uint4 xv = *reinterpret_cast<const uint4*>(&x5[(size_t)node * 128 + li * 8]);
        float xr[8] = {bfu_lo(xv.x), bfu_hi(xv.x), bfu_lo(xv.y), bfu_hi(xv.y),
                       bfu_lo(xv.z), bfu_hi(xv.z), bfu_lo(xv.w), bfu_hi(xv.w)};
        #pragma unroll
        for (int j = 0; j < 8; j++) {
            int d = li * 8 + j;
            float x7 = xr[j] + fmaxf(dn * acc[j] + b2[d], 0.f);
            s1 += x7 * wfc2[d];
            s2 += x7 * wc3[d];
        }
    }
    #pragma unroll
    for (int o = 32; o > 0; o >>= 1) {
        s1 += __shfl_down(s1, o);
        s2 += __shfl_down(s2, o);
    }
    if (lane == 0) {
        out[node] = s1 + bfc2[0] + bc3[0];
        xw3[node] = s2 * dn;                   // pre-scale for agg1
    }
}

__global__ __launch_bounds__(256) void k_agg1_csr(const float* __restrict__ sv,
                                                  const int* __restrict__ rowptr,
                                                  const ushort* __restrict__ csr16,
                                                  const float* __restrict__ dis,
                                                  float* __restrict__ out, int n) {
    int i = blockIdx.x * 256 + threadIdx.x;
    if (i >= n) return;
    int s = rowptr[i], t = rowptr[i + 1];
    float a = 0.f;
    #pragma unroll 4
    for (int p = s; p < t; ++p) a += sv[csr16[p]];
    out[i] += dis[i] * a;
}

// ---------------- weight fragment packing (single merged launch) ----------------
__global__ __launch_bounds__(256) void k_prepW(const float* __restrict__ w0,
                                               const float* __restrict__ w1,
                                               const float* __restrict__ wf1,
                                               const float* __restrict__ wf2,
                                               ushort* __restrict__ W0f,
                                               ushort* __restrict__ W1f,
                                               ushort* __restrict__ Bf) {
    int id = blockIdx.x * 256 + threadIdx.x;   // 8192 + 16384 = 24576
    if (id < 8192) {
        int mat = id >> 12;
        int rem = id & 4095;                   // arr*2048 + k0i*1024 + nt*64 + lane
        int lane = rem & 63;
        int nt = (rem >> 6) & 15;
        int k0i = (rem >> 10) & 1;
        int arr = rem >> 11;
        const float* w = mat ? w1 : w0;
        ushort* dst = mat ? W1f : W0f;
        int n = nt * 16 + (lane & 15);
        int kb = k0i * 32 + (lane >> 4) * 8;
        ushort o[8];
        #pragma unroll
        for (int j = 0; j < 8; j++) {
            float v = w[(size_t)(kb + j) * 256 + n];
            o[j] = arr ? bf16_bits(v - bf16_val(v)) : bf16_bits(v);
        }
        *reinterpret_cast<int4*>(&dst[(size_t)rem * 8]) = *reinterpret_cast<const int4*>(o);
    } else if (id < 24576) {
        int rem = id - 8192;                   // 16*16*64
        int lane = rem & 63;
        int nt   = (rem >> 6) & 15;
        int k0i  = (rem >> 10) & 15;
        int n = nt * 16 + (lane & 15);
        int kbase = k0i * 32 + (lane >> 4) * 8;
        ushort outv[8];
        #pragma unroll
        for (int j = 0; j < 8; j++) {
            int k = kbase + j;
            float v = (n < 128) ? wf1[(size_t)k * 128 + n]
                                : wf2[(size_t)k * 128 + (n - 128)];
            outv[j] = bf16_bits(v);
        }
        *reinterpret_cast<int4*>(&Bf[(size_t)rem * 8]) = *reinterpret_cast<const int4*>(outv);
    }
}

// ---------------- fused MFMA GEMM chain (64-row blocks, 8 waves) ----------------
// r6: forced pipelining via inline-asm loads + counted vmcnt + sched_barrier.
// r2-r5 forensics: hipcc re-sinks C++ prefetch to JIT order (VGPR stuck at 64,
// dur invariant ~46us, ~70% latency stall). asm volatile loads cannot be sunk,
// their dst regs must stay live -> real prefetch depth.
//   phase 1: issue all 16 layer loads -> vmcnt(0) -> 64 MFMAs (one latency
//            window per layer; layer-1 issue overlapped with layer-0 epilogue)
//   phase 2: 4-deep rotating B prefetch, steady-state s_waitcnt vmcnt(6)
//            (drain tail 4/2/0); A frags 1-deep C++ ds_read (lgkm tracked by
//            compiler). sched_barrier(0) after each wait: MFMAs consuming asm
//            outputs would otherwise be hoisted past the wait (rule #18).
//
// Phase 3 stages the C tile in LDS so global stores are wide contiguous uint4
// (r3 fix: WRITE_SIZE 40.7 -> 25.1MB).
//
// LDS fragment layout (per 512-ushort block):
//   inner = (qf*16 + row)*8 + j, XOR-swizzled:
//   inner ^= ((inner>>6)&1)<<4 ^ ((inner>>7)&1)<<3
// GF(2) bijection applied identically on write and read; conflict-free
// (verified: SQ_LDS_BANK_CONFLICT == 0).
__device__ __forceinline__ int x3_swz(int inner) {
    return inner ^ ((((inner >> 6) & 1) << 4) ^ (((inner >> 7) & 1) << 3));
}

__global__ __launch_bounds__(512) void k_mmfused(
    const ushort* __restrict__ xh, const ushort* __restrict__ ah_,
    const ushort* __restrict__ W0f, const ushort* __restrict__ W1f,
    const float* __restrict__ b0, const float* __restrict__ b1,
    const ushort* __restrict__ Bf, const float* __restrict__ bias1,
    const float* __restrict__ dis,
    ushort* __restrict__ C1, ushort* __restrict__ C2, int M) {
    __shared__ ushort x3[4 * 16 * 512];      // 64KB: [mt(4)][k0(16)][512 frag block]

    const int t = threadIdx.x;
    const int lane = t & 63;
    const int wv = t >> 6;                   // 0..7
    const int m0 = blockIdx.x * 64;
    const int ln15 = lane & 15;
    const int quad = lane >> 4;

    f32x4 acc[4][2];

    // ---- phase 1: two layers of K=64 GEMM (2-term weight split) -> LDS ----
    // issue all 16 loads of a layer (asm, cannot be sunk), single vmcnt(0).
    auto issueLayer = [&](const ushort* A, const ushort* Wf,
                          uint4e (&wS)[8], uint4e (&aS)[8]) {
        #pragma unroll
        for (int k0i = 0; k0i < 2; k0i++) {
            #pragma unroll
            for (int ntl = 0; ntl < 2; ntl++) {
                const ushort* pw = Wf + ((size_t)k0i * 16 + wv * 2 + ntl) * 512 + (size_t)lane * 8;
                gload16(wS[k0i * 4 + ntl * 2 + 0], pw);
                gload16(wS[k0i * 4 + ntl * 2 + 1], pw + 16384);   // lo-residual
            }
            #pragma unroll
            for (int mt = 0; mt < 4; mt++) {
                int gm = m0 + mt * 16 + ln15;
                int gmc = gm < M - 1 ? gm : M - 1;   // clamp tail rows
                gload16(aS[k0i * 4 + mt], &A[(size_t)gmc * 64 + k0i * 32 + quad * 8]);
            }
        }
    };
    auto mfmaLayer = [&](uint4e (&wS)[8], uint4e (&aS)[8]) {
        #pragma unroll
        for (int mt = 0; mt < 4; mt++)
            #pragma unroll
            for (int ntl = 0; ntl < 2; ntl++)
                acc[mt][ntl] = (f32x4){0.f, 0.f, 0.f, 0.f};
        #pragma unroll
        for (int k0i = 0; k0i < 2; k0i++) {
            #pragma unroll
            for (int mt = 0; mt < 4; mt++) {
                short8 a = __builtin_bit_cast(short8, aS[k0i * 4 + mt]);
                // all-hi then all-lo across ntl: breaks dependent acc chains
                #pragma unroll
                for (int ntl = 0; ntl < 2; ntl++)
                    acc[mt][ntl] = __builtin_amdgcn_mfma_f32_16x16x32_bf16(
                        a, __builtin_bit_cast(short8, wS[k0i * 4 + ntl * 2 + 0]), acc[mt][ntl], 0, 0, 0);
                #pragma unroll
                for (int ntl = 0; ntl < 2; ntl++)
                    acc[mt][ntl] = __builtin_amdgcn_mfma_f32_16x16x32_bf16(
                        a, __builtin_bit_cast(short8, wS[k0i * 4 + ntl * 2 + 1]), acc[mt][ntl], 0, 0, 0);
            }
        }
    };
    auto epiLayer = [&](const float* bias, int layer) {
        #pragma unroll
        for (int mt = 0; mt < 4; mt++) {
            #pragma unroll
            for (int ntl = 0; ntl < 2; ntl++) {
                int gn = (wv * 2 + ntl) * 16 + ln15;     // local col 0..255
                int gcol = gn + layer * 256;             // x3 col 0..511
                int k0f = gcol >> 5, qf = (gcol >> 3) & 3, j = gcol & 7;
                #pragma unroll
                for (int r = 0; r < 4; r++) {
                    int rloc = quad * 4 + r;             // row within 16-row tile
                    float v = fmaxf(acc[mt][ntl][r] + bias[gn], 0.f);
                    int inner = x3_swz((qf * 16 + rloc) * 8 + j);
                    x3[(mt * 16 + k0f) * 512 + inner] = bf16_bits(v);
                }
            }
        }
    };

    {
        uint4e wS0[8], aS0[8], wS1[8], aS1[8];
        issueLayer(xh, W0f, wS0, aS0);
        asm volatile("s_waitcnt vmcnt(0)" ::: "memory");
        __builtin_amdgcn_sched_barrier(0);
        mfmaLayer(wS0, aS0);
        issueLayer(ah_, W1f, wS1, aS1);      // L1 latency hides under L0 epilogue
        epiLayer(b0, 0);
        asm volatile("s_waitcnt vmcnt(0)" ::: "memory");
        __builtin_amdgcn_sched_barrier(0);
        mfmaLayer(wS1, aS1);
        epiLayer(b1, 1);
    }
    __syncthreads();

    // ---- phase 2: x3(LDS) @ Bf, forced 4-deep asm B prefetch ----
    #pragma unroll
    for (int mt = 0; mt < 4; mt++)
        #pragma unroll
        for (int ntl = 0; ntl < 2; ntl++)
            acc[mt][ntl] = (f32x4){0.f, 0.f, 0.f, 0.f};

    const int innerA = x3_swz(lane * 8);     // per-lane A-frag offset (swizzled)
    const ushort* bPtr = Bf + ((size_t)wv * 2) * 512 + (size_t)lane * 8;

    auto ldA = [&](int k0, short8* dst) {
        #pragma unroll
        for (int mt = 0; mt < 4; mt++)
            dst[mt] = *reinterpret_cast<const short8*>(&x3[(mt * 16 + k0) * 512 + innerA]);
    };

    uint4e bb[4][2];                         // rotating 4-deep B buffers
    short8 aC[4], aN[4];

#define ISSUE_B(K0) { \
    gload16(bb[(K0) & 3][0], bPtr + ((size_t)(K0) * 16 + 0) * 512); \
    gload16(bb[(K0) & 3][1], bPtr + ((size_t)(K0) * 16 + 1) * 512); }

// steady-state: outstanding = buffers k0..k0+3 (8 loads); wait to 6 retires
// k0's pair. MFMAs consume, then refill buffer (k0&3) for k0+4 (depth 3-4).
#define P2_STEP(K0, VMSTR) { \
    if ((K0) < 15) ldA((K0) + 1, aN); \
    asm volatile("s_waitcnt " VMSTR ::: "memory"); \
    __builtin_amdgcn_sched_barrier(0); \
    short8 bc0 = __builtin_bit_cast(short8, bb[(K0) & 3][0]); \
    short8 bc1 = __builtin_bit_cast(short8, bb[(K0) & 3][1]); \
    _Pragma("unroll") \
    for (int mt = 0; mt < 4; mt++) { \
        acc[mt][0] = __builtin_amdgcn_mfma_f32_16x16x32_bf16(aC[mt], bc0, acc[mt][0], 0, 0, 0); \
        acc[mt][1] = __builtin_amdgcn_mfma_f32_16x16x32_bf16(aC[mt], bc1, acc[mt][1], 0, 0, 0); \
    } \
    if ((K0) < 12) ISSUE_B((K0) + 4); \
    _Pragma("unroll") \
    for (int mt = 0; mt < 4; mt++) aC[mt] = aN[mt]; }

    ISSUE_B(0); ISSUE_B(1); ISSUE_B(2); ISSUE_B(3);
    ldA(0, aC);
    P2_STEP(0,  "vmcnt(6)");  P2_STEP(1,  "vmcnt(6)");
    P2_STEP(2,  "vmcnt(6)");  P2_STEP(3,  "vmcnt(6)");
    P2_STEP(4,  "vmcnt(6)");  P2_STEP(5,  "vmcnt(6)");
    P2_STEP(6,  "vmcnt(6)");  P2_STEP(7,  "vmcnt(6)");
    P2_STEP(8,  "vmcnt(6)");  P2_STEP(9,  "vmcnt(6)");
    P2_STEP(10, "vmcnt(6)");  P2_STEP(11, "vmcnt(6)");
    P2_STEP(12, "vmcnt(6)");  P2_STEP(13, "vmcnt(4)");
    P2_STEP(14, "vmcnt(2)");  P2_STEP(15, "vmcnt(0)");
#undef P2_STEP
#undef ISSUE_B

    __syncthreads();   // all x3 reads done before the C-tile overwrites it

    // ---- phase 3: C fragments -> LDS [64][256] tile -> wide linear stores ----
    // Stage swizzle: ushort idx = row64*256 + gn, idx ^= ((row64>>2)&3)<<4.
    // Per store-instr the 4 quads land in 4 distinct 16-ushort blocks ->
    // 2 lanes/bank (free). Linear read applies the same XOR per row.
    #pragma unroll
    for (int mt = 0; mt < 4; mt++) {
        float dn[4];
        #pragma unroll
        for (int r = 0; r < 4; r++) {
            int gm = m0 + mt * 16 + quad * 4 + r;
            dn[r] = (gm < M) ? dis[gm] : 0.f;
        }
        #pragma unroll
        for (int ntl = 0; ntl < 2; ntl++) {
            int gn = (wv * 2 + ntl) * 16 + ln15;   // 0..255
            #pragma unroll
            for (int r = 0; r < 4; r++) {
                int row64 = mt * 16 + quad * 4 + r;
                float v = acc[mt][ntl][r];
                ushort ov = (gn < 128) ? bf16_bits(fmaxf(v + bias1[gn], 0.f))
                                       : bf16_bits(v * dn[r]);
                int idx = row64 * 256 + gn;
                idx ^= ((row64 >> 2) & 3) << 4;
                x3[idx] = ov;
            }
        }
    }
    __syncthreads();

    #pragma unroll
    for (int c = 0; c < 4; c++) {
        int offu = c * 4096 + t * 8;            // ushort offset, contiguous per c
        int row64 = offu >> 8;
        int colu = offu & 255;
        int src = row64 * 256 + (colu ^ (((row64 >> 2) & 3) << 4));
        uint4 v = *reinterpret_cast<const uint4*>(&x3[src]);
        int gm = m0 + row64;
        if (gm < M) {
            if (colu < 128)
                *reinterpret_cast<uint4*>(&C1[(size_t)gm * 128 + colu]) = v;
            else
                *reinterpret_cast<uint4*>(&C2[(size_t)gm * 128 + (colu - 128)]) = v;
        }
    }
}

extern "C" void kernel_launch(void* const* d_in, const int* in_sizes, int n_in,
                              void* d_out, int out_size, void* d_ws, size_t ws_size,
                              hipStream_t stream) {
    const float* x       = (const float*)d_in[0];
    const int*   ei      = (const int*)d_in[1];
    const float* w_fc    = (const float*)d_in[2];
    const float* b_fc    = (const float*)d_in[3];
    const float* w_conv1 = (const float*)d_in[4];
    const float* b_conv1 = (const float*)d_in[5];
    const float* w_fc1   = (const float*)d_in[6];
    const float* b_fc1   = (const float*)d_in[7];
    const float* w_conv2 = (const float*)d_in[8];
    const float* b_conv2 = (const float*)d_in[9];
    const float* w_fc2   = (const float*)d_in[10];
    const float* b_fc2   = (const float*)d_in[11];
    const float* w_conv3 = (const float*)d_in[12];
    const float* b_conv3 = (const float*)d_in[13];

    const int N = in_sizes[0] / 64;       // 50000
    const int E = in_sizes[1] / 2;        // 800000
    const int* row = ei;
    const int* col = ei + E;

    const int nb = (N + 255) / 256;       // 196 buckets
    const int nblk = (N + 63) / 64;       // 782 (64-row blocks, fused GEMM)

    // workspace layout. alloc() takes 4-BYTE units (chunks padded to 16B).
    char* p = (char*)d_ws;
    auto alloc = [&](size_t elems) {
        void* q = p; p += ((elems + 3) & ~(size_t)3) * 4; return q;
    };
    int*    bcnt    = (int*)   alloc(200);
    int*    bbase   = (int*)   alloc(200);
    int*    bcur    = (int*)   alloc(200);
    int*    rowptr  = (int*)   alloc(N + 4);
    uint*   stage   = (uint*)  alloc(E);                   // packed (col<<16|row)
    ushort* csr16   = (ushort*)alloc((size_t)E / 2);       // 2B row index per edge
    float*  dis     = (float*) alloc(N);
    ushort* xh      = (ushort*)alloc((size_t)N * 32);      // N*64 bf16 = N*32 words
    ushort* xs      = (ushort*)alloc((size_t)N * 32);      // dis-scaled gather copy
    ushort* agghi   = (ushort*)alloc((size_t)N * 32);
    ushort* Bf      = (ushort*)alloc(65536);               // single bf16
    ushort* W0f     = (ushort*)alloc(16384);
    ushort* W1f     = (ushort*)alloc(16384);
    ushort* x5      = (ushort*)alloc((size_t)N * 64);      // N*128 bf16
    ushort* xw2     = (ushort*)alloc((size_t)N * 64);      // N*128 bf16
    float*  xw3     = (float*) alloc(N);

    float* out = (float*)d_out;

    // ---- CSR build (count-free) ----
    hipMemsetAsync(bcnt, 0, 196 * sizeof(int), stream);
    k_bcount<<<(E + 2047) / 2048, 256, 0, stream>>>(col, bcnt, E);
    k_bscan<<<1, 256, 0, stream>>>(bcnt, bbase, bcur, E);
    k_binA<<<(E + 2047) / 2048, 256, 0, stream>>>(row, col, bcur, stage, E);
    k_binB<<<nb, 256, 0, stream>>>(stage, bbase, rowptr, dis, csr16, N, E);

    // input split (+dis-scaled copy) + weight fragment packing
    k_prepX<<<(N * 16 + 255) / 256, 256, 0, stream>>>(x, dis, xh, xs, N * 16);
    k_prepW<<<24576 / 256, 256, 0, stream>>>(w_fc, w_conv1, w_fc1, w_conv2,
                                             W0f, W1f, Bf);

    // conv1 propagate: agg = dis[col] * sum xs[row], wide-granule gather
    k_agg64_csr<<<(N + 3) / 4, 256, 0, stream>>>(xs, rowptr, csr16, dis, agghi, N);

    // fused: x1/x2 layers -> LDS x3 tile -> x5 = relu(x3@w_fc1+b), xw2 = dis*(x3@w_conv2)
    k_mmfused<<<nblk, 512, 0, stream>>>(xh, agghi, W0f, W1f, b_fc, b_conv1,
                                        Bf, b_fc1, dis, x5, xw2, N);

    // x7 in registers (wide-granule gather); fused dual dot -> out, xw3
    k_agg128_x7dot<<<(N + 3) / 4, 256, 0, stream>>>(
        xw2, rowptr, csr16, dis, b_conv2, x5,
        w_fc2, b_fc2, w_conv3, b_conv3, out, xw3, N);

    // out += dis[i] * sum xw3[row]
    k_agg1_csr<<<(N + 255) / 256, 256, 0, stream>>>(xw3, rowptr, csr16, dis, out, N);
}

// Round 7
// 243.243 us; speedup vs baseline: 1.0454x; 1.0454x over previous
//
#include <hip/hip_runtime.h>
#include <hip/hip_bf16.h>

typedef __attribute__((ext_vector_type(8))) short short8;
typedef __attribute__((ext_vector_type(4))) float f32x4;

__device__ __forceinline__ ushort bf16_bits(float v) {
    __hip_bfloat16 h = __float2bfloat16(v);
    return *reinterpret_cast<ushort*>(&h);
}
__device__ __forceinline__ float bf16_val(float v) {
    __hip_bfloat16 h = __float2bfloat16(v);
    return __bfloat162float(h);
}
__device__ __forceinline__ float bfu_lo(uint u) {
    uint t = u << 16; return __uint_as_float(t);
}
__device__ __forceinline__ float bfu_hi(uint u) {
    uint t = u & 0xffff0000u; return __uint_as_float(t);
}

// ---------------- CSR build (count-free: degrees computed in binB) ----------------

// merged setup: blocks [0,nbc) = bucket count histogram; blocks [nbc,..) =
// weight fragment packing (was a separate 96-block underfilled launch).
__global__ __launch_bounds__(256) void k_setup(const int* __restrict__ col,
                                               int* __restrict__ bcnt, int E, int nbc,
                                               const float* __restrict__ w0,
                                               const float* __restrict__ w1,
                                               const float* __restrict__ wf1,
                                               const float* __restrict__ wf2,
                                               ushort* __restrict__ W0f,
                                               ushort* __restrict__ W1f,
                                               ushort* __restrict__ Bf) {
    if ((int)blockIdx.x < nbc) {
        __shared__ int hist[196];
        int tid = threadIdx.x;
        int base = blockIdx.x * 2048;
        if (tid < 196) hist[tid] = 0;
        __syncthreads();
        #pragma unroll
        for (int i = 0; i < 8; i++) {
            int e = base + i * 256 + tid;
            if (e < E) atomicAdd(&hist[col[e] >> 8], 1);
        }
        __syncthreads();
        if (tid < 196 && hist[tid] > 0) atomicAdd(&bcnt[tid], hist[tid]);
        return;
    }
    int id = (blockIdx.x - nbc) * 256 + threadIdx.x;   // 8192 + 16384 = 24576
    if (id < 8192) {
        int mat = id >> 12;
        int rem = id & 4095;                   // arr*2048 + k0i*1024 + nt*64 + lane
        int lane = rem & 63;
        int nt = (rem >> 6) & 15;
        int k0i = (rem >> 10) & 1;
        int arr = rem >> 11;
        const float* w = mat ? w1 : w0;
        ushort* dst = mat ? W1f : W0f;
        int n = nt * 16 + (lane & 15);
        int kb = k0i * 32 + (lane >> 4) * 8;
        ushort o[8];
        #pragma unroll
        for (int j = 0; j < 8; j++) {
            float v = w[(size_t)(kb + j) * 256 + n];
            o[j] = arr ? bf16_bits(v - bf16_val(v)) : bf16_bits(v);
        }
        *reinterpret_cast<int4*>(&dst[(size_t)rem * 8]) = *reinterpret_cast<const int4*>(o);
    } else if (id < 24576) {
        int rem = id - 8192;                   // 16*16*64
        int lane = rem & 63;
        int nt   = (rem >> 6) & 15;
        int k0i  = (rem >> 10) & 15;
        int n = nt * 16 + (lane & 15);
        int kbase = k0i * 32 + (lane >> 4) * 8;
        ushort outv[8];
        #pragma unroll
        for (int j = 0; j < 8; j++) {
            int k = kbase + j;
            float v = (n < 128) ? wf1[(size_t)k * 128 + n]
                                : wf2[(size_t)k * 128 + (n - 128)];
            outv[j] = bf16_bits(v);
        }
        *reinterpret_cast<int4*>(&Bf[(size_t)rem * 8]) = *reinterpret_cast<const int4*>(outv);
    }
}

__global__ __launch_bounds__(256) void k_bscan(const int* __restrict__ bcnt,
                                               int* __restrict__ bbase,
                                               int* __restrict__ bcur, int E) {
    int i = threadIdx.x;
    int v = (i < 196) ? bcnt[i] : 0;
    int lane = i & 63, w = i >> 6;
    int s = v;
    #pragma unroll
    for (int o = 1; o < 64; o <<= 1) {
        int t = __shfl_up(s, o);
        if (lane >= o) s += t;
    }
    __shared__ int wsum[4];
    if (lane == 63) wsum[w] = s;
    __syncthreads();
    int add = 0;
    for (int ww = 0; ww < w; ww++) add += wsum[ww];
    int excl = s + add - v;
    if (i < 196) {
        bbase[i] = excl;
        bcur[i] = excl;
    }
    if (i == 195) bbase[196] = excl + v;   // == E
}

__global__ __launch_bounds__(256) void k_binA(const int* __restrict__ row,
                                              const int* __restrict__ col,
                                              int* __restrict__ bcur,
                                              uint* __restrict__ stage, int E) {
    __shared__ uint colbuf[2048];
    __shared__ int hist[196];
    __shared__ int lcur[196];
    int tid = threadIdx.x;
    int base = blockIdx.x * 2048;
    if (tid < 196) hist[tid] = 0;
    __syncthreads();
    #pragma unroll
    for (int i = 0; i < 8; i++) {
        int e = base + i * 256 + tid;
        uint c = 0xFFFFFFFFu;
        if (e < E) {
            c = (uint)col[e];
            atomicAdd(&hist[c >> 8], 1);
        }
        colbuf[i * 256 + tid] = c;
    }
    __syncthreads();
    if (tid < 196 && hist[tid] > 0) lcur[tid] = atomicAdd(&bcur[tid], hist[tid]);
    __syncthreads();
    #pragma unroll
    for (int i = 0; i < 8; i++) {
        int idx = i * 256 + tid;
        uint c = colbuf[idx];
        if (c != 0xFFFFFFFFu) {
            uint r = (uint)row[base + idx];
            int p = atomicAdd(&lcur[c >> 8], 1);
            stage[p] = (c << 16) | r;
        }
    }
}

__global__ __launch_bounds__(256) void k_binB(const uint* __restrict__ stage,
                                              const int* __restrict__ bbase,
                                              int* __restrict__ rowptr,
                                              float* __restrict__ dis,
                                              ushort* __restrict__ csr16,
                                              int n, int E) {
    __shared__ int cnt[256];
    __shared__ int cur[256];
    __shared__ int wsum[4];
    int b = blockIdx.x;
    int lo = b << 8;
    int tid = threadIdx.x;
    int gstart = bbase[b], gend = bbase[b + 1];
    cnt[tid] = 0;
    __syncthreads();
    for (int idx = gstart + tid; idx < gend; idx += 256)
        atomicAdd(&cnt[(stage[idx] >> 16) & 255], 1);
    __syncthreads();
    int v = cnt[tid];
    int lane = tid & 63, w = tid >> 6;
    int s = v;
    #pragma unroll
    for (int o = 1; o < 64; o <<= 1) {
        int t = __shfl_up(s, o);
        if (lane >= o) s += t;
    }
    if (lane == 63) wsum[w] = s;
    __syncthreads();
    int add = 0;
    for (int ww = 0; ww < w; ww++) add += wsum[ww];
    int excl = s + add - v + gstart;
    int node = lo + tid;
    if (node < n) {
        rowptr[node] = excl;
        dis[node] = v > 0 ? rsqrtf((float)v) : 0.f;
    }
    cur[tid] = excl;
    if (tid == 0 && b == gridDim.x - 1) rowptr[n] = E;
    __syncthreads();
    for (int idx = gstart + tid; idx < gend; idx += 256) {
        uint pk = stage[idx];
        int p = atomicAdd(&cur[(pk >> 16) & 255], 1);
        csr16[p] = (ushort)(pk & 0xffffu);
    }
}

// ---------------- input split: x -> bf16 + dis-scaled bf16 copy ----------------

__global__ __launch_bounds__(256) void k_prepX(const float* __restrict__ x,
                                               const float* __restrict__ dis,
                                               ushort* __restrict__ xh,
                                               ushort* __restrict__ xs, int total4) {
    int i = blockIdx.x * 256 + threadIdx.x;
    if (i >= total4) return;
    float4 v = reinterpret_cast<const float4*>(x)[i];
    float dn = dis[i >> 4];                  // node = (i*4)/64
    float vv[4] = {v.x, v.y, v.z, v.w};
    uint hv[2], sv[2];
    #pragma unroll
    for (int g = 0; g < 2; g++) {
        float a0 = vv[g * 2], a1 = vv[g * 2 + 1];
        hv[g] = (uint)bf16_bits(a0) | ((uint)bf16_bits(a1) << 16);
        sv[g] = (uint)bf16_bits(a0 * dn) | ((uint)bf16_bits(a1 * dn) << 16);
    }
    reinterpret_cast<uint2*>(xh)[i] = make_uint2(hv[0], hv[1]);
    reinterpret_cast<uint2*>(xs)[i] = make_uint2(sv[0], sv[1]);
}

// ---------------- CSR aggregations (gather, no atomics) ----------------

// agg[i] = dis[i] * sum_e xs[row_e], wide-granule: lane = sub(0..7)*8+li(0..7);
// uint4/lane -> 8 rows (1KB) per instruction. Output single bf16 (hi only).
__global__ __launch_bounds__(256) void k_agg64_csr(const ushort* __restrict__ xs,
                                                   const int* __restrict__ rowptr,
                                                   const ushort* __restrict__ csr16,
                                                   const float* __restrict__ dis,
                                                   ushort* __restrict__ agghi, int n) {
    int node = blockIdx.x * 4 + (threadIdx.x >> 6);
    if (node >= n) return;
    int lane = threadIdx.x & 63;
    int sub = lane >> 3;          // edge slot 0..7
    int li  = lane & 7;           // dim group: dims li*8 .. li*8+7
    int s = rowptr[node], t = rowptr[node + 1];
    float acc[8] = {};
    int p = s;
    for (; p + 16 <= t; p += 16) {
        int rr[2];
        #pragma unroll
        for (int u = 0; u < 2; u++) rr[u] = csr16[p + u * 8 + sub];
        uint4 v[2];
        #pragma unroll
        for (int u = 0; u < 2; u++)
            v[u] = *reinterpret_cast<const uint4*>(&xs[(size_t)rr[u] * 64 + li * 8]);
        #pragma unroll
        for (int u = 0; u < 2; u++) {
            acc[0] += bfu_lo(v[u].x); acc[1] += bfu_hi(v[u].x);
            acc[2] += bfu_lo(v[u].y); acc[3] += bfu_hi(v[u].y);
            acc[4] += bfu_lo(v[u].z); acc[5] += bfu_hi(v[u].z);
            acc[6] += bfu_lo(v[u].w); acc[7] += bfu_hi(v[u].w);
        }
    }
    for (; p < t; p += 8) {
        int e = p + sub;
        if (e < t) {
            int rr = csr16[e];
            uint4 v = *reinterpret_cast<const uint4*>(&xs[(size_t)rr * 64 + li * 8]);
            acc[0] += bfu_lo(v.x); acc[1] += bfu_hi(v.x);
            acc[2] += bfu_lo(v.y); acc[3] += bfu_hi(v.y);
            acc[4] += bfu_lo(v.z); acc[5] += bfu_hi(v.z);
            acc[6] += bfu_lo(v.w); acc[7] += bfu_hi(v.w);
        }
    }
    #pragma unroll
    for (int j = 0; j < 8; j++) {
        acc[j] += __shfl_xor(acc[j], 8);
        acc[j] += __shfl_xor(acc[j], 16);
        acc[j] += __shfl_xor(acc[j], 32);
    }
    if (sub == 0) {
        float dn = dis[node];
        uint hp[4];
        #pragma unroll
        for (int g = 0; g < 4; g++) {
            float a0 = acc[g * 2] * dn, a1 = acc[g * 2 + 1] * dn;
            hp[g] = (uint)bf16_bits(a0) | ((uint)bf16_bits(a1) << 16);
        }
        *reinterpret_cast<uint4*>(&agghi[(size_t)node * 64 + li * 8]) =
            make_uint4(hp[0], hp[1], hp[2], hp[3]);
    }
}

// Fused x7 + dual dot, wide-granule gather: lane = sub(0..3)*16 + li(0..15);
// uint4/lane -> 4 rows (1KB) per instruction. x5 is packed bf16.
__global__ __launch_bounds__(256) void k_agg128_x7dot(
    const ushort* __restrict__ xw,
    const int* __restrict__ rowptr,
    const ushort* __restrict__ csr16,
    const float* __restrict__ dis,
    const float* __restrict__ b2,
    const ushort* __restrict__ x5,
    const float* __restrict__ wfc2, const float* __restrict__ bfc2,
    const float* __restrict__ wc3,  const float* __restrict__ bc3,
    float* __restrict__ out, float* __restrict__ xw3, int n) {
    int node = blockIdx.x * 4 + (threadIdx.x >> 6);
    if (node >= n) return;
    int lane = threadIdx.x & 63;
    int sub = lane >> 4;          // edge slot 0..3
    int li  = lane & 15;          // dim group: dims li*8 .. li*8+7
    int s = rowptr[node], t = rowptr[node + 1];
    float acc[8] = {};
    int p = s;
    for (; p + 16 <= t; p += 16) {
        int rr[4];
        #pragma unroll
        for (int u = 0; u < 4; u++) rr[u] = csr16[p + u * 4 + sub];
        uint4 v[4];
        #pragma unroll
        for (int u = 0; u < 4; u++)
            v[u] = *reinterpret_cast<const uint4*>(&xw[(size_t)rr[u] * 128 + li * 8]);
        #pragma unroll
        for (int u = 0; u < 4; u++) {
            acc[0] += bfu_lo(v[u].x); acc[1] += bfu_hi(v[u].x);
            acc[2] += bfu_lo(v[u].y); acc[3] += bfu_hi(v[u].y);
            acc[4] += bfu_lo(v[u].z); acc[5] += bfu_hi(v[u].z);
            acc[6] += bfu_lo(v[u].w); acc[7] += bfu_hi(v[u].w);
        }
    }
    for (; p < t; p += 4) {
        int e = p + sub;
        if (e < t) {
            int rr = csr16[e];
            uint4 v = *reinterpret_cast<const uint4*>(&xw[(size_t)rr * 128 + li * 8]);
            acc[0] += bfu_lo(v.x); acc[1] += bfu_hi(v.x);
            acc[2] += bfu_lo(v.y); acc[3] += bfu_hi(v.y);
            acc[4] += bfu_lo(v.z); acc[5] += bfu_hi(v.z);
            acc[6] += bfu_lo(v.w); acc[7] += bfu_hi(v.w);
        }
    }
    #pragma unroll
    for (int j = 0; j < 8; j++) {
        acc[j] += __shfl_xor(acc[j], 16);
        acc[j] += __shfl_xor(acc[j], 32);
    }
    float dn = dis[node];
    float s1 = 0.f, s2 = 0.f;
    if (sub == 0) {
        uint4 xv = *reinterpret_cast<const uint4*>(&x5[(size_t)node * 128 + li * 8]);
        float xr[8] = {bfu_lo(xv.x), bfu_hi(xv.x), bfu_lo(xv.y), bfu_hi(xv.y),
                       bfu_lo(xv.z), bfu_hi(xv.z), bfu_lo(xv.w), bfu_hi(xv.w)};
        #pragma unroll
        for (int j = 0; j < 8; j++) {
            int d = li * 8 + j;
            float x7 = xr[j] + fmaxf(dn * acc[j] + b2[d], 0.f);
            s1 += x7 * wfc2[d];
            s2 += x7 * wc3[d];
        }
    }
    #pragma unroll
    for (int o = 32; o > 0; o >>= 1) {
        s1 += __shfl_down(s1, o);
        s2 += __shfl_down(s2, o);
    }
    if (lane == 0) {
        out[node] = s1 + bfc2[0] + bc3[0];
        xw3[node] = s2 * dn;                   // pre-scale for agg1
    }
}

__global__ __launch_bounds__(256) void k_agg1_csr(const float* __restrict__ sv,
                                                  const int* __restrict__ rowptr,
                                                  const ushort* __restrict__ csr16,
                                                  const float* __restrict__ dis,
                                                  float* __restrict__ out, int n) {
    int i = blockIdx.x * 256 + threadIdx.x;
    if (i >= n) return;
    int s = rowptr[i], t = rowptr[i + 1];
    float a = 0.f;
    #pragma unroll 4
    for (int p = s; p < t; ++p) a += sv[csr16[p]];
    out[i] += dis[i] * a;
}

// ---------------- fused MFMA GEMM chain (64-row blocks, 8 waves) ----------------
// One block = 512 threads = 8 waves, 64 rows. CONVERGED at ~46us (= 428 TF
// effective for the 19.7 GFLOP chain; above the m102 shape-curve reference for
// comparable small-K/small-N shapes). Six structural variants (occupancy 2x,
// B-traffic 1/2, store fix, C++ prefetch, asm vmcnt pipeline) all landed
// 45.5-57us -> shape-bound plateau, not scheduling. asm pipeline REGRESSED
// (57us: sched_barrier lockstep convoys) -- do not reintroduce.
//
// Phase 3 stages the C tile in LDS so global stores are wide contiguous uint4
// (r3 fix: WRITE_SIZE 40.7 -> 25.1MB).
//
// LDS fragment layout (per 512-ushort block):
//   inner = (qf*16 + row)*8 + j, XOR-swizzled:
//   inner ^= ((inner>>6)&1)<<4 ^ ((inner>>7)&1)<<3
// GF(2) bijection applied identically on write and read; conflict-free
// (verified: SQ_LDS_BANK_CONFLICT == 0).
__device__ __forceinline__ int x3_swz(int inner) {
    return inner ^ ((((inner >> 6) & 1) << 4) ^ (((inner >> 7) & 1) << 3));
}

__global__ __launch_bounds__(512) void k_mmfused(
    const ushort* __restrict__ xh, const ushort* __restrict__ ah_,
    const ushort* __restrict__ W0f, const ushort* __restrict__ W1f,
    const float* __restrict__ b0, const float* __restrict__ b1,
    const ushort* __restrict__ Bf, const float* __restrict__ bias1,
    const float* __restrict__ dis,
    ushort* __restrict__ C1, ushort* __restrict__ C2, int M) {
    __shared__ ushort x3[4 * 16 * 512];      // 64KB: [mt(4)][k0(16)][512 frag block]

    const int t = threadIdx.x;
    const int lane = t & 63;
    const int wv = t >> 6;                   // 0..7
    const int m0 = blockIdx.x * 64;
    const int ln15 = lane & 15;
    const int quad = lane >> 4;

    f32x4 acc[4][2];

    // ---- phase 1: two layers of K=64 GEMM (2-term weight split) -> LDS ----
    #pragma unroll
    for (int layer = 0; layer < 2; layer++) {
        const ushort* A = layer ? ah_ : xh;
        const ushort* Wf = layer ? W1f : W0f;
        const float* bias = layer ? b1 : b0;
        #pragma unroll
        for (int mt = 0; mt < 4; mt++)
            #pragma unroll
            for (int ntl = 0; ntl < 2; ntl++)
                acc[mt][ntl] = (f32x4){0.f, 0.f, 0.f, 0.f};

        // hoist ALL loads for this layer: 8 W-frag pairs + 8 A-frags,
        // then the 64 MFMAs -> one overlapped latency window, not eight.
        short8 wh[2][2], wl[2][2], av[2][4];
        #pragma unroll
        for (int k0i = 0; k0i < 2; k0i++) {
            #pragma unroll
            for (int ntl = 0; ntl < 2; ntl++) {
                const ushort* pw = Wf + ((size_t)k0i * 16 + wv * 2 + ntl) * 512 + (size_t)lane * 8;
                wh[k0i][ntl] = *reinterpret_cast<const short8*>(pw);
                wl[k0i][ntl] = *reinterpret_cast<const short8*>(pw + 16384);   // lo-residual
            }
            #pragma unroll
            for (int mt = 0; mt < 4; mt++) {
                int gm = m0 + mt * 16 + ln15;
                int gmc = gm < M - 1 ? gm : M - 1;   // clamp tail rows
                size_t ia = (size_t)gmc * 64 + k0i * 32 + quad * 8;
                av[k0i][mt] = *reinterpret_cast<const short8*>(&A[ia]);
            }
        }
        #pragma unroll
        for (int k0i = 0; k0i < 2; k0i++) {
            #pragma unroll
            for (int mt = 0; mt < 4; mt++) {
                // all-hi then all-lo across ntl: breaks dependent acc chains
                #pragma unroll
                for (int ntl = 0; ntl < 2; ntl++)
                    acc[mt][ntl] = __builtin_amdgcn_mfma_f32_16x16x32_bf16(av[k0i][mt], wh[k0i][ntl], acc[mt][ntl], 0, 0, 0);
                #pragma unroll
                for (int ntl = 0; ntl < 2; ntl++)
                    acc[mt][ntl] = __builtin_amdgcn_mfma_f32_16x16x32_bf16(av[k0i][mt], wl[k0i][ntl], acc[mt][ntl], 0, 0, 0);
            }
        }

        // epilogue: relu(acc+bias) -> swizzled LDS fragment scatter
        #pragma unroll
        for (int mt = 0; mt < 4; mt++) {
            #pragma unroll
            for (int ntl = 0; ntl < 2; ntl++) {
                int gn = (wv * 2 + ntl) * 16 + ln15;     // local col 0..255
                int gcol = gn + layer * 256;             // x3 col 0..511
                int k0f = gcol >> 5, qf = (gcol >> 3) & 3, j = gcol & 7;
                #pragma unroll
                for (int r = 0; r < 4; r++) {
                    int rloc = quad * 4 + r;             // row within 16-row tile
                    float v = fmaxf(acc[mt][ntl][r] + bias[gn], 0.f);
                    int inner = x3_swz((qf * 16 + rloc) * 8 + j);
                    x3[(mt * 16 + k0f) * 512 + inner] = bf16_bits(v);
                }
            }
        }
    }
    __syncthreads();

    // ---- phase 2: x3(LDS) @ Bf, 4-deep B prefetch + 1-deep A prefetch ----
    #pragma unroll
    for (int mt = 0; mt < 4; mt++)
        #pragma unroll
        for (int ntl = 0; ntl < 2; ntl++)
            acc[mt][ntl] = (f32x4){0.f, 0.f, 0.f, 0.f};

    const int innerA = x3_swz(lane * 8);     // per-lane A-frag offset (swizzled)
    const ushort* bPtr = Bf + ((size_t)wv * 2) * 512 + (size_t)lane * 8;

    auto ldB = [&](int k0, short8* dst) {
        #pragma unroll
        for (int ntl = 0; ntl < 2; ntl++)
            dst[ntl] = *reinterpret_cast<const short8*>(bPtr + ((size_t)k0 * 16 + ntl) * 512);
    };
    auto ldA = [&](int k0, short8* dst) {
        #pragma unroll
        for (int mt = 0; mt < 4; mt++)
            dst[mt] = *reinterpret_cast<const short8*>(&x3[(mt * 16 + k0) * 512 + innerA]);
    };

    short8 b0r[2], b1r[2], b2r[2], b3r[2];
    short8 aC[4], aN[4];
    ldB(0, b0r); ldB(1, b1r); ldB(2, b2r); ldB(3, b3r);
    ldA(0, aC);

    #pragma unroll
    for (int k4 = 0; k4 < 4; k4++) {
        #pragma unroll
        for (int j = 0; j < 4; j++) {
            const int k0 = k4 * 4 + j;
            short8* bcur = (j == 0) ? b0r : (j == 1) ? b1r : (j == 2) ? b2r : b3r;
            // prefetch B for k0+4 (clamped reload of 0 past the end: harmless)
            short8 tB[2];
            int kpre = k0 + 4 < 16 ? k0 + 4 : 0;
            ldB(kpre, tB);
            // prefetch A-frags for k0+1
            int ka = k0 + 1 < 16 ? k0 + 1 : 0;
            ldA(ka, aN);
            #pragma unroll
            for (int mt = 0; mt < 4; mt++)
                #pragma unroll
                for (int ntl = 0; ntl < 2; ntl++)
                    acc[mt][ntl] = __builtin_amdgcn_mfma_f32_16x16x32_bf16(aC[mt], bcur[ntl], acc[mt][ntl], 0, 0, 0);
            bcur[0] = tB[0]; bcur[1] = tB[1];
            #pragma unroll
            for (int mt = 0; mt < 4; mt++) aC[mt] = aN[mt];
        }
    }
    __syncthreads();   // all x3 reads done before the C-tile overwrites it

    // ---- phase 3: C fragments -> LDS [64][256] tile -> wide linear stores ----
    // Stage swizzle: ushort idx = row64*256 + gn, idx ^= ((row64>>2)&3)<<4.
    // Per store-instr the 4 quads land in 4 distinct 16-ushort blocks ->
    // 2 lanes/bank (free). Linear read applies the same XOR per row.
    #pragma unroll
    for (int mt = 0; mt < 4; mt++) {
        float dn[4];
        #pragma unroll
        for (int r = 0; r < 4; r++) {
            int gm = m0 + mt * 16 + quad * 4 + r;
            dn[r] = (gm < M) ? dis[gm] : 0.f;
        }
        #pragma unroll
        for (int ntl = 0; ntl < 2; ntl++) {
            int gn = (wv * 2 + ntl) * 16 + ln15;   // 0..255
            #pragma unroll
            for (int r = 0; r < 4; r++) {
                int row64 = mt * 16 + quad * 4 + r;
                float v = acc[mt][ntl][r];
                ushort ov = (gn < 128) ? bf16_bits(fmaxf(v + bias1[gn], 0.f))
                                       : bf16_bits(v * dn[r]);
                int idx = row64 * 256 + gn;
                idx ^= ((row64 >> 2) & 3) << 4;
                x3[idx] = ov;
            }
        }
    }
    __syncthreads();

    #pragma unroll
    for (int c = 0; c < 4; c++) {
        int offu = c * 4096 + t * 8;            // ushort offset, contiguous per c
        int row64 = offu >> 8;
        int colu = offu & 255;
        int src = row64 * 256 + (colu ^ (((row64 >> 2) & 3) << 4));
        uint4 v = *reinterpret_cast<const uint4*>(&x3[src]);
        int gm = m0 + row64;
        if (gm < M) {
            if (colu < 128)
                *reinterpret_cast<uint4*>(&C1[(size_t)gm * 128 + colu]) = v;
            else
                *reinterpret_cast<uint4*>(&C2[(size_t)gm * 128 + (colu - 128)]) = v;
        }
    }
}

extern "C" void kernel_launch(void* const* d_in, const int* in_sizes, int n_in,
                              void* d_out, int out_size, void* d_ws, size_t ws_size,
                              hipStream_t stream) {
    const float* x       = (const float*)d_in[0];
    const int*   ei      = (const int*)d_in[1];
    const float* w_fc    = (const float*)d_in[2];
    const float* b_fc    = (const float*)d_in[3];
    const float* w_conv1 = (const float*)d_in[4];
    const float* b_conv1 = (const float*)d_in[5];
    const float* w_fc1   = (const float*)d_in[6];
    const float* b_fc1   = (const float*)d_in[7];
    const float* w_conv2 = (const float*)d_in[8];
    const float* b_conv2 = (const float*)d_in[9];
    const float* w_fc2   = (const float*)d_in[10];
    const float* b_fc2   = (const float*)d_in[11];
    const float* w_conv3 = (const float*)d_in[12];
    const float* b_conv3 = (const float*)d_in[13];

    const int N = in_sizes[0] / 64;       // 50000
    const int E = in_sizes[1] / 2;        // 800000
    const int* row = ei;
    const int* col = ei + E;

    const int nb = (N + 255) / 256;       // 196 buckets
    const int nbc = (E + 2047) / 2048;    // 391 bucket-count blocks
    const int nblk = (N + 63) / 64;       // 782 (64-row blocks, fused GEMM)

    // workspace layout. alloc() takes 4-BYTE units (chunks padded to 16B).
    char* p = (char*)d_ws;
    auto alloc = [&](size_t elems) {
        void* q = p; p += ((elems + 3) & ~(size_t)3) * 4; return q;
    };
    int*    bcnt    = (int*)   alloc(200);
    int*    bbase   = (int*)   alloc(200);
    int*    bcur    = (int*)   alloc(200);
    int*    rowptr  = (int*)   alloc(N + 4);
    uint*   stage   = (uint*)  alloc(E);                   // packed (col<<16|row)
    ushort* csr16   = (ushort*)alloc((size_t)E / 2);       // 2B row index per edge
    float*  dis     = (float*) alloc(N);
    ushort* xh      = (ushort*)alloc((size_t)N * 32);      // N*64 bf16 = N*32 words
    ushort* xs      = (ushort*)alloc((size_t)N * 32);      // dis-scaled gather copy
    ushort* agghi   = (ushort*)alloc((size_t)N * 32);
    ushort* Bf      = (ushort*)alloc(65536);               // single bf16
    ushort* W0f     = (ushort*)alloc(16384);
    ushort* W1f     = (ushort*)alloc(16384);
    ushort* x5      = (ushort*)alloc((size_t)N * 64);      // N*128 bf16
    ushort* xw2     = (ushort*)alloc((size_t)N * 64);      // N*128 bf16
    float*  xw3     = (float*) alloc(N);

    float* out = (float*)d_out;

    // ---- CSR build (count-free) + weight packing (merged into k_setup) ----
    hipMemsetAsync(bcnt, 0, 196 * sizeof(int), stream);
    k_setup<<<nbc + 96, 256, 0, stream>>>(col, bcnt, E, nbc,
                                          w_fc, w_conv1, w_fc1, w_conv2,
                                          W0f, W1f, Bf);
    k_bscan<<<1, 256, 0, stream>>>(bcnt, bbase, bcur, E);
    k_binA<<<(E + 2047) / 2048, 256, 0, stream>>>(row, col, bcur, stage, E);
    k_binB<<<nb, 256, 0, stream>>>(stage, bbase, rowptr, dis, csr16, N, E);

    // input split (+dis-scaled copy)
    k_prepX<<<(N * 16 + 255) / 256, 256, 0, stream>>>(x, dis, xh, xs, N * 16);

    // conv1 propagate: agg = dis[col] * sum xs[row], wide-granule gather
    k_agg64_csr<<<(N + 3) / 4, 256, 0, stream>>>(xs, rowptr, csr16, dis, agghi, N);

    // fused: x1/x2 layers -> LDS x3 tile -> x5 = relu(x3@w_fc1+b), xw2 = dis*(x3@w_conv2)
    k_mmfused<<<nblk, 512, 0, stream>>>(xh, agghi, W0f, W1f, b_fc, b_conv1,
                                        Bf, b_fc1, dis, x5, xw2, N);

    // x7 in registers (wide-granule gather); fused dual dot -> out, xw3
    k_agg128_x7dot<<<(N + 3) / 4, 256, 0, stream>>>(
        xw2, rowptr, csr16, dis, b_conv2, x5,
        w_fc2, b_fc2, w_conv3, b_conv3, out, xw3, N);

    // out += dis[i] * sum xw3[row]
    k_agg1_csr<<<(N + 255) / 256, 256, 0, stream>>>(xw3, rowptr, csr16, dis, out, N);
}

// Round 8
// 241.077 us; speedup vs baseline: 1.0548x; 1.0090x over previous
//
#include <hip/hip_runtime.h>
#include <hip/hip_bf16.h>

typedef __attribute__((ext_vector_type(8))) short short8;
typedef __attribute__((ext_vector_type(4))) float f32x4;

__device__ __forceinline__ ushort bf16_bits(float v) {
    __hip_bfloat16 h = __float2bfloat16(v);
    return *reinterpret_cast<ushort*>(&h);
}
__device__ __forceinline__ float bf16_val(float v) {
    __hip_bfloat16 h = __float2bfloat16(v);
    return __bfloat162float(h);
}
__device__ __forceinline__ float bfu_lo(uint u) {
    uint t = u << 16; return __uint_as_float(t);
}
__device__ __forceinline__ float bfu_hi(uint u) {
    uint t = u & 0xffff0000u; return __uint_as_float(t);
}

// ---------------- CSR build (count-free: degrees computed in binB) ----------------

// merged setup: blocks [0,nbc) = bucket count histogram; blocks [nbc,..) =
// weight fragment packing (was a separate underfilled launch).
__global__ __launch_bounds__(256) void k_setup(const int* __restrict__ col,
                                               int* __restrict__ bcnt, int E, int nbc,
                                               const float* __restrict__ w0,
                                               const float* __restrict__ w1,
                                               const float* __restrict__ wf1,
                                               const float* __restrict__ wf2,
                                               ushort* __restrict__ W0f,
                                               ushort* __restrict__ W1f,
                                               ushort* __restrict__ Bf) {
    if ((int)blockIdx.x < nbc) {
        __shared__ int hist[196];
        int tid = threadIdx.x;
        int base = blockIdx.x * 2048;
        if (tid < 196) hist[tid] = 0;
        __syncthreads();
        #pragma unroll
        for (int i = 0; i < 8; i++) {
            int e = base + i * 256 + tid;
            if (e < E) atomicAdd(&hist[col[e] >> 8], 1);
        }
        __syncthreads();
        if (tid < 196 && hist[tid] > 0) atomicAdd(&bcnt[tid], hist[tid]);
        return;
    }
    int id = (blockIdx.x - nbc) * 256 + threadIdx.x;   // 8192 + 16384 = 24576
    if (id < 8192) {
        int mat = id >> 12;
        int rem = id & 4095;                   // arr*2048 + k0i*1024 + nt*64 + lane
        int lane = rem & 63;
        int nt = (rem >> 6) & 15;
        int k0i = (rem >> 10) & 1;
        int arr = rem >> 11;
        const float* w = mat ? w1 : w0;
        ushort* dst = mat ? W1f : W0f;
        int n = nt * 16 + (lane & 15);
        int kb = k0i * 32 + (lane >> 4) * 8;
        ushort o[8];
        #pragma unroll
        for (int j = 0; j < 8; j++) {
            float v = w[(size_t)(kb + j) * 256 + n];
            o[j] = arr ? bf16_bits(v - bf16_val(v)) : bf16_bits(v);
        }
        *reinterpret_cast<int4*>(&dst[(size_t)rem * 8]) = *reinterpret_cast<const int4*>(o);
    } else if (id < 24576) {
        int rem = id - 8192;                   // 16*16*64
        int lane = rem & 63;
        int nt   = (rem >> 6) & 15;
        int k0i  = (rem >> 10) & 15;
        int n = nt * 16 + (lane & 15);
        int kbase = k0i * 32 + (lane >> 4) * 8;
        ushort outv[8];
        #pragma unroll
        for (int j = 0; j < 8; j++) {
            int k = kbase + j;
            float v = (n < 128) ? wf1[(size_t)k * 128 + n]
                                : wf2[(size_t)k * 128 + (n - 128)];
            outv[j] = bf16_bits(v);
        }
        *reinterpret_cast<int4*>(&Bf[(size_t)rem * 8]) = *reinterpret_cast<const int4*>(outv);
    }
}

// binA: local recompute of the 196-bucket exclusive scan (replaces the
// serializing 1-block k_bscan); bcur is a zero-based global cursor.
__global__ __launch_bounds__(256) void k_binA(const int* __restrict__ row,
                                              const int* __restrict__ col,
                                              const int* __restrict__ bcnt,
                                              int* __restrict__ bcur,
                                              uint* __restrict__ stage, int E) {
    __shared__ uint colbuf[2048];
    __shared__ int hist[196];
    __shared__ int lcur[196];
    __shared__ int wsum[4];
    int tid = threadIdx.x;
    int base = blockIdx.x * 2048;
    if (tid < 196) hist[tid] = 0;
    __syncthreads();
    #pragma unroll
    for (int i = 0; i < 8; i++) {
        int e = base + i * 256 + tid;
        uint c = 0xFFFFFFFFu;
        if (e < E) {
            c = (uint)col[e];
            atomicAdd(&hist[c >> 8], 1);
        }
        colbuf[i * 256 + tid] = c;
    }
    __syncthreads();
    // local exclusive scan of global bcnt -> bucket base
    int v = (tid < 196) ? bcnt[tid] : 0;
    int lane = tid & 63, w = tid >> 6;
    int s = v;
    #pragma unroll
    for (int o = 1; o < 64; o <<= 1) {
        int t2 = __shfl_up(s, o);
        if (lane >= o) s += t2;
    }
    if (lane == 63) wsum[w] = s;
    __syncthreads();
    int add = 0;
    for (int ww = 0; ww < w; ww++) add += wsum[ww];
    int excl = s + add - v;
    if (tid < 196 && hist[tid] > 0)
        lcur[tid] = excl + atomicAdd(&bcur[tid], hist[tid]);
    __syncthreads();
    #pragma unroll
    for (int i = 0; i < 8; i++) {
        int idx = i * 256 + tid;
        uint c = colbuf[idx];
        if (c != 0xFFFFFFFFu) {
            uint r = (uint)row[base + idx];
            int p = atomicAdd(&lcur[c >> 8], 1);
            stage[p] = (c << 16) | r;
        }
    }
}

// binB: local bucket-scan for [gstart,gend); also absorbs k_prepX for its own
// 256 nodes (dis kept in LDS -> no global dis round-trip, one less launch).
__global__ __launch_bounds__(256) void k_binB(const uint* __restrict__ stage,
                                              const int* __restrict__ bcnt,
                                              int* __restrict__ rowptr,
                                              float* __restrict__ dis,
                                              ushort* __restrict__ csr16,
                                              const float* __restrict__ x,
                                              ushort* __restrict__ xh,
                                              ushort* __restrict__ xs,
                                              int n, int E) {
    __shared__ int cnt[256];
    __shared__ int cur[256];
    __shared__ int wsum[4];
    __shared__ int sgse[2];
    __shared__ float sdis[256];
    int b = blockIdx.x;
    int lo = b << 8;
    int tid = threadIdx.x;

    // bucket-level exclusive scan of bcnt -> this block's stage range
    {
        int v = (tid < 196) ? bcnt[tid] : 0;
        int lane = tid & 63, w = tid >> 6;
        int s = v;
        #pragma unroll
        for (int o = 1; o < 64; o <<= 1) {
            int t2 = __shfl_up(s, o);
            if (lane >= o) s += t2;
        }
        if (lane == 63) wsum[w] = s;
        __syncthreads();
        int add = 0;
        for (int ww = 0; ww < w; ww++) add += wsum[ww];
        int excl = s + add - v;
        if (tid == b) { sgse[0] = excl; sgse[1] = excl + v; }
    }
    cnt[tid] = 0;
    __syncthreads();
    int gstart = sgse[0], gend = sgse[1];
    for (int idx = gstart + tid; idx < gend; idx += 256)
        atomicAdd(&cnt[(stage[idx] >> 16) & 255], 1);
    __syncthreads();
    int v = cnt[tid];
    int lane = tid & 63, w = tid >> 6;
    int s = v;
    #pragma unroll
    for (int o = 1; o < 64; o <<= 1) {
        int t2 = __shfl_up(s, o);
        if (lane >= o) s += t2;
    }
    if (lane == 63) wsum[w] = s;
    __syncthreads();
    int add = 0;
    for (int ww = 0; ww < w; ww++) add += wsum[ww];
    int excl = s + add - v + gstart;
    int node = lo + tid;
    float d = v > 0 ? rsqrtf((float)v) : 0.f;
    if (node < n) {
        rowptr[node] = excl;
        dis[node] = d;
    }
    sdis[tid] = d;
    cur[tid] = excl;
    if (tid == 0 && b == gridDim.x - 1) rowptr[n] = E;
    __syncthreads();
    for (int idx = gstart + tid; idx < gend; idx += 256) {
        uint pk = stage[idx];
        int p = atomicAdd(&cur[(pk >> 16) & 255], 1);
        csr16[p] = (ushort)(pk & 0xffffu);
    }

    // ---- absorbed prepX: convert this block's 256 nodes (4096 float4) ----
    #pragma unroll
    for (int i = 0; i < 16; i++) {
        int li = i * 256 + tid;                  // local float4 idx 0..4095
        int nl = li >> 4;                        // local node 0..255
        if (lo + nl >= n) break;
        size_t gf = (size_t)b * 4096 + li;       // global float4 idx
        float4 vv = reinterpret_cast<const float4*>(x)[gf];
        float dn = sdis[nl];
        float a[4] = {vv.x, vv.y, vv.z, vv.w};
        uint hv[2], sv[2];
        #pragma unroll
        for (int g = 0; g < 2; g++) {
            float a0 = a[g * 2], a1 = a[g * 2 + 1];
            hv[g] = (uint)bf16_bits(a0) | ((uint)bf16_bits(a1) << 16);
            sv[g] = (uint)bf16_bits(a0 * dn) | ((uint)bf16_bits(a1 * dn) << 16);
        }
        reinterpret_cast<uint2*>(xh)[gf] = make_uint2(hv[0], hv[1]);
        reinterpret_cast<uint2*>(xs)[gf] = make_uint2(sv[0], sv[1]);
    }
}

// ---------------- CSR aggregations (gather, no atomics) ----------------

// agg[i] = dis[i] * sum_e xs[row_e], wide-granule: lane = sub(0..7)*8+li(0..7);
// uint4/lane -> 8 rows (1KB) per instruction. Output single bf16 (hi only).
// Tail = single masked 16-edge batch (keeps gathers in flight for low-deg nodes).
__global__ __launch_bounds__(256) void k_agg64_csr(const ushort* __restrict__ xs,
                                                   const int* __restrict__ rowptr,
                                                   const ushort* __restrict__ csr16,
                                                   const float* __restrict__ dis,
                                                   ushort* __restrict__ agghi, int n) {
    int node = blockIdx.x * 4 + (threadIdx.x >> 6);
    if (node >= n) return;
    int lane = threadIdx.x & 63;
    int sub = lane >> 3;          // edge slot 0..7
    int li  = lane & 7;           // dim group: dims li*8 .. li*8+7
    int s = rowptr[node], t = rowptr[node + 1];
    float acc[8] = {};
    int p = s;
    for (; p + 16 <= t; p += 16) {
        int rr[2];
        #pragma unroll
        for (int u = 0; u < 2; u++) rr[u] = csr16[p + u * 8 + sub];
        uint4 v[2];
        #pragma unroll
        for (int u = 0; u < 2; u++)
            v[u] = *reinterpret_cast<const uint4*>(&xs[(size_t)rr[u] * 64 + li * 8]);
        #pragma unroll
        for (int u = 0; u < 2; u++) {
            acc[0] += bfu_lo(v[u].x); acc[1] += bfu_hi(v[u].x);
            acc[2] += bfu_lo(v[u].y); acc[3] += bfu_hi(v[u].y);
            acc[4] += bfu_lo(v[u].z); acc[5] += bfu_hi(v[u].z);
            acc[6] += bfu_lo(v[u].w); acc[7] += bfu_hi(v[u].w);
        }
    }
    if (p < t) {                  // <=15 remaining: one predicated batch
        bool ok[2]; int rr[2];
        #pragma unroll
        for (int u = 0; u < 2; u++) {
            int e = p + u * 8 + sub;
            ok[u] = e < t;
            rr[u] = csr16[ok[u] ? e : s];
        }
        uint4 v[2];
        #pragma unroll
        for (int u = 0; u < 2; u++)
            v[u] = *reinterpret_cast<const uint4*>(&xs[(size_t)rr[u] * 64 + li * 8]);
        #pragma unroll
        for (int u = 0; u < 2; u++) {
            if (ok[u]) {
                acc[0] += bfu_lo(v[u].x); acc[1] += bfu_hi(v[u].x);
                acc[2] += bfu_lo(v[u].y); acc[3] += bfu_hi(v[u].y);
                acc[4] += bfu_lo(v[u].z); acc[5] += bfu_hi(v[u].z);
                acc[6] += bfu_lo(v[u].w); acc[7] += bfu_hi(v[u].w);
            }
        }
    }
    #pragma unroll
    for (int j = 0; j < 8; j++) {
        acc[j] += __shfl_xor(acc[j], 8);
        acc[j] += __shfl_xor(acc[j], 16);
        acc[j] += __shfl_xor(acc[j], 32);
    }
    if (sub == 0) {
        float dn = dis[node];
        uint hp[4];
        #pragma unroll
        for (int g = 0; g < 4; g++) {
            float a0 = acc[g * 2] * dn, a1 = acc[g * 2 + 1] * dn;
            hp[g] = (uint)bf16_bits(a0) | ((uint)bf16_bits(a1) << 16);
        }
        *reinterpret_cast<uint4*>(&agghi[(size_t)node * 64 + li * 8]) =
            make_uint4(hp[0], hp[1], hp[2], hp[3]);
    }
}

// Fused x7 + dual dot, wide-granule gather: lane = sub(0..3)*16 + li(0..15);
// uint4/lane -> 4 rows (1KB) per instruction. x5 is packed bf16.
__global__ __launch_bounds__(256) void k_agg128_x7dot(
    const ushort* __restrict__ xw,
    const int* __restrict__ rowptr,
    const ushort* __restrict__ csr16,
    const float* __restrict__ dis,
    const float* __restrict__ b2,
    const ushort* __restrict__ x5,
    const float* __restrict__ wfc2, const float* __restrict__ bfc2,
    const float* __restrict__ wc3,  const float* __restrict__ bc3,
    float* __restrict__ out, float* __restrict__ xw3, int n) {
    int node = blockIdx.x * 4 + (threadIdx.x >> 6);
    if (node >= n) return;
    int lane = threadIdx.x & 63;
    int sub = lane >> 4;          // edge slot 0..3
    int li  = lane & 15;          // dim group: dims li*8 .. li*8+7
    int s = rowptr[node], t = rowptr[node + 1];
    float acc[8] = {};
    int p = s;
    for (; p + 16 <= t; p += 16) {
        int rr[4];
        #pragma unroll
        for (int u = 0; u < 4; u++) rr[u] = csr16[p + u * 4 + sub];
        uint4 v[4];
        #pragma unroll
        for (int u = 0; u < 4; u++)
            v[u] = *reinterpret_cast<const uint4*>(&xw[(size_t)rr[u] * 128 + li * 8]);
        #pragma unroll
        for (int u = 0; u < 4; u++) {
            acc[0] += bfu_lo(v[u].x); acc[1] += bfu_hi(v[u].x);
            acc[2] += bfu_lo(v[u].y); acc[3] += bfu_hi(v[u].y);
            acc[4] += bfu_lo(v[u].z); acc[5] += bfu_hi(v[u].z);
            acc[6] += bfu_lo(v[u].w); acc[7] += bfu_hi(v[u].w);
        }
    }
    if (p < t) {                  // <=15 remaining: one predicated batch
        bool ok[4]; int rr[4];
        #pragma unroll
        for (int u = 0; u < 4; u++) {
            int e = p + u * 4 + sub;
            ok[u] = e < t;
            rr[u] = csr16[ok[u] ? e : s];
        }
        uint4 v[4];
        #pragma unroll
        for (int u = 0; u < 4; u++)
            v[u] = *reinterpret_cast<const uint4*>(&xw[(size_t)rr[u] * 128 + li * 8]);
        #pragma unroll
        for (int u = 0; u < 4; u++) {
            if (ok[u]) {
                acc[0] += bfu_lo(v[u].x); acc[1] += bfu_hi(v[u].x);
                acc[2] += bfu_lo(v[u].y); acc[3] += bfu_hi(v[u].y);
                acc[4] += bfu_lo(v[u].z); acc[5] += bfu_hi(v[u].z);
                acc[6] += bfu_lo(v[u].w); acc[7] += bfu_hi(v[u].w);
            }
        }
    }
    #pragma unroll
    for (int j = 0; j < 8; j++) {
        acc[j] += __shfl_xor(acc[j], 16);
        acc[j] += __shfl_xor(acc[j], 32);
    }
    float dn = dis[node];
    float s1 = 0.f, s2 = 0.f;
    if (sub == 0) {
        uint4 xv = *reinterpret_cast<const uint4*>(&x5[(size_t)node * 128 + li * 8]);
        float xr[8] = {bfu_lo(xv.x), bfu_hi(xv.x), bfu_lo(xv.y), bfu_hi(xv.y),
                       bfu_lo(xv.z), bfu_hi(xv.z), bfu_lo(xv.w), bfu_hi(xv.w)};
        #pragma unroll
        for (int j = 0; j < 8; j++) {
            int d = li * 8 + j;
            float x7 = xr[j] + fmaxf(dn * acc[j] + b2[d], 0.f);
            s1 += x7 * wfc2[d];
            s2 += x7 * wc3[d];
        }
    }
    #pragma unroll
    for (int o = 32; o > 0; o >>= 1) {
        s1 += __shfl_down(s1, o);
        s2 += __shfl_down(s2, o);
    }
    if (lane == 0) {
        out[node] = s1 + bfc2[0] + bc3[0];
        xw3[node] = s2 * dn;                   // pre-scale for agg1
    }
}

// one 16-lane group per node (was 1 thread/node on a 196-block grid -> CUs
// underfilled; now 3125 blocks, edge-parallel + shfl reduce).
__global__ __launch_bounds__(256) void k_agg1_csr(const float* __restrict__ sv,
                                                  const int* __restrict__ rowptr,
                                                  const ushort* __restrict__ csr16,
                                                  const float* __restrict__ dis,
                                                  float* __restrict__ out, int n) {
    int grp = threadIdx.x >> 4, l16 = threadIdx.x & 15;
    int node = blockIdx.x * 16 + grp;
    if (node >= n) return;
    int s = rowptr[node], t = rowptr[node + 1];
    float a = 0.f;
    for (int p = s + l16; p < t; p += 16) a += sv[csr16[p]];
    a += __shfl_xor(a, 1);
    a += __shfl_xor(a, 2);
    a += __shfl_xor(a, 4);
    a += __shfl_xor(a, 8);
    if (l16 == 0) out[node] += dis[node] * a;
}

// ---------------- fused MFMA GEMM chain (64-row blocks, 8 waves) ----------------
// CONVERGED at ~46us (428 TF effective for the 19.7 GFLOP chain). Six
// structural variants (occupancy 2x, B-traffic 1/2, store fix, C++ prefetch,
// asm vmcnt pipeline) all landed 45.5-57us -> shape-bound plateau. The asm
// pipeline REGRESSED (57us: sched_barrier lockstep convoys) - do not redo.
__device__ __forceinline__ int x3_swz(int inner) {
    return inner ^ ((((inner >> 6) & 1) << 4) ^ (((inner >> 7) & 1) << 3));
}

__global__ __launch_bounds__(512) void k_mmfused(
    const ushort* __restrict__ xh, const ushort* __restrict__ ah_,
    const ushort* __restrict__ W0f, const ushort* __restrict__ W1f,
    const float* __restrict__ b0, const float* __restrict__ b1,
    const ushort* __restrict__ Bf, const float* __restrict__ bias1,
    const float* __restrict__ dis,
    ushort* __restrict__ C1, ushort* __restrict__ C2, int M) {
    __shared__ ushort x3[4 * 16 * 512];      // 64KB: [mt(4)][k0(16)][512 frag block]

    const int t = threadIdx.x;
    const int lane = t & 63;
    const int wv = t >> 6;                   // 0..7
    const int m0 = blockIdx.x * 64;
    const int ln15 = lane & 15;
    const int quad = lane >> 4;

    f32x4 acc[4][2];

    // ---- phase 1: two layers of K=64 GEMM (2-term weight split) -> LDS ----
    #pragma unroll
    for (int layer = 0; layer < 2; layer++) {
        const ushort* A = layer ? ah_ : xh;
        const ushort* Wf = layer ? W1f : W0f;
        const float* bias = layer ? b1 : b0;
        #pragma unroll
        for (int mt = 0; mt < 4; mt++)
            #pragma unroll
            for (int ntl = 0; ntl < 2; ntl++)
                acc[mt][ntl] = (f32x4){0.f, 0.f, 0.f, 0.f};

        short8 wh[2][2], wl[2][2], av[2][4];
        #pragma unroll
        for (int k0i = 0; k0i < 2; k0i++) {
            #pragma unroll
            for (int ntl = 0; ntl < 2; ntl++) {
                const ushort* pw = Wf + ((size_t)k0i * 16 + wv * 2 + ntl) * 512 + (size_t)lane * 8;
                wh[k0i][ntl] = *reinterpret_cast<const short8*>(pw);
                wl[k0i][ntl] = *reinterpret_cast<const short8*>(pw + 16384);   // lo-residual
            }
            #pragma unroll
            for (int mt = 0; mt < 4; mt++) {
                int gm = m0 + mt * 16 + ln15;
                int gmc = gm < M - 1 ? gm : M - 1;   // clamp tail rows
                size_t ia = (size_t)gmc * 64 + k0i * 32 + quad * 8;
                av[k0i][mt] = *reinterpret_cast<const short8*>(&A[ia]);
            }
        }
        #pragma unroll
        for (int k0i = 0; k0i < 2; k0i++) {
            #pragma unroll
            for (int mt = 0; mt < 4; mt++) {
                #pragma unroll
                for (int ntl = 0; ntl < 2; ntl++)
                    acc[mt][ntl] = __builtin_amdgcn_mfma_f32_16x16x32_bf16(av[k0i][mt], wh[k0i][ntl], acc[mt][ntl], 0, 0, 0);
                #pragma unroll
                for (int ntl = 0; ntl < 2; ntl++)
                    acc[mt][ntl] = __builtin_amdgcn_mfma_f32_16x16x32_bf16(av[k0i][mt], wl[k0i][ntl], acc[mt][ntl], 0, 0, 0);
            }
        }

        #pragma unroll
        for (int mt = 0; mt < 4; mt++) {
            #pragma unroll
            for (int ntl = 0; ntl < 2; ntl++) {
                int gn = (wv * 2 + ntl) * 16 + ln15;     // local col 0..255
                int gcol = gn + layer * 256;             // x3 col 0..511
                int k0f = gcol >> 5, qf = (gcol >> 3) & 3, j = gcol & 7;
                #pragma unroll
                for (int r = 0; r < 4; r++) {
                    int rloc = quad * 4 + r;
                    float v = fmaxf(acc[mt][ntl][r] + bias[gn], 0.f);
                    int inner = x3_swz((qf * 16 + rloc) * 8 + j);
                    x3[(mt * 16 + k0f) * 512 + inner] = bf16_bits(v);
                }
            }
        }
    }
    __syncthreads();

    // ---- phase 2: x3(LDS) @ Bf, 4-deep B prefetch + 1-deep A prefetch ----
    #pragma unroll
    for (int mt = 0; mt < 4; mt++)
        #pragma unroll
        for (int ntl = 0; ntl < 2; ntl++)
            acc[mt][ntl] = (f32x4){0.f, 0.f, 0.f, 0.f};

    const int innerA = x3_swz(lane * 8);
    const ushort* bPtr = Bf + ((size_t)wv * 2) * 512 + (size_t)lane * 8;

    auto ldB = [&](int k0, short8* dst) {
        #pragma unroll
        for (int ntl = 0; ntl < 2; ntl++)
            dst[ntl] = *reinterpret_cast<const short8*>(bPtr + ((size_t)k0 * 16 + ntl) * 512);
    };
    auto ldA = [&](int k0, short8* dst) {
        #pragma unroll
        for (int mt = 0; mt < 4; mt++)
            dst[mt] = *reinterpret_cast<const short8*>(&x3[(mt * 16 + k0) * 512 + innerA]);
    };

    short8 b0r[2], b1r[2], b2r[2], b3r[2];
    short8 aC[4], aN[4];
    ldB(0, b0r); ldB(1, b1r); ldB(2, b2r); ldB(3, b3r);
    ldA(0, aC);

    #pragma unroll
    for (int k4 = 0; k4 < 4; k4++) {
        #pragma unroll
        for (int j = 0; j < 4; j++) {
            const int k0 = k4 * 4 + j;
            short8* bcur = (j == 0) ? b0r : (j == 1) ? b1r : (j == 2) ? b2r : b3r;
            short8 tB[2];
            int kpre = k0 + 4 < 16 ? k0 + 4 : 0;
            ldB(kpre, tB);
            int ka = k0 + 1 < 16 ? k0 + 1 : 0;
            ldA(ka, aN);
            #pragma unroll
            for (int mt = 0; mt < 4; mt++)
                #pragma unroll
                for (int ntl = 0; ntl < 2; ntl++)
                    acc[mt][ntl] = __builtin_amdgcn_mfma_f32_16x16x32_bf16(aC[mt], bcur[ntl], acc[mt][ntl], 0, 0, 0);
            bcur[0] = tB[0]; bcur[1] = tB[1];
            #pragma unroll
            for (int mt = 0; mt < 4; mt++) aC[mt] = aN[mt];
        }
    }
    __syncthreads();

    // ---- phase 3: C fragments -> LDS [64][256] tile -> wide linear stores ----
    #pragma unroll
    for (int mt = 0; mt < 4; mt++) {
        float dn[4];
        #pragma unroll
        for (int r = 0; r < 4; r++) {
            int gm = m0 + mt * 16 + quad * 4 + r;
            dn[r] = (gm < M) ? dis[gm] : 0.f;
        }
        #pragma unroll
        for (int ntl = 0; ntl < 2; ntl++) {
            int gn = (wv * 2 + ntl) * 16 + ln15;
            #pragma unroll
            for (int r = 0; r < 4; r++) {
                int row64 = mt * 16 + quad * 4 + r;
                float v = acc[mt][ntl][r];
                ushort ov = (gn < 128) ? bf16_bits(fmaxf(v + bias1[gn], 0.f))
                                       : bf16_bits(v * dn[r]);
                int idx = row64 * 256 + gn;
                idx ^= ((row64 >> 2) & 3) << 4;
                x3[idx] = ov;
            }
        }
    }
    __syncthreads();

    #pragma unroll
    for (int c = 0; c < 4; c++) {
        int offu = c * 4096 + t * 8;
        int row64 = offu >> 8;
        int colu = offu & 255;
        int src = row64 * 256 + (colu ^ (((row64 >> 2) & 3) << 4));
        uint4 v = *reinterpret_cast<const uint4*>(&x3[src]);
        int gm = m0 + row64;
        if (gm < M) {
            if (colu < 128)
                *reinterpret_cast<uint4*>(&C1[(size_t)gm * 128 + colu]) = v;
            else
                *reinterpret_cast<uint4*>(&C2[(size_t)gm * 128 + (colu - 128)]) = v;
        }
    }
}

extern "C" void kernel_launch(void* const* d_in, const int* in_sizes, int n_in,
                              void* d_out, int out_size, void* d_ws, size_t ws_size,
                              hipStream_t stream) {
    const float* x       = (const float*)d_in[0];
    const int*   ei      = (const int*)d_in[1];
    const float* w_fc    = (const float*)d_in[2];
    const float* b_fc    = (const float*)d_in[3];
    const float* w_conv1 = (const float*)d_in[4];
    const float* b_conv1 = (const float*)d_in[5];
    const float* w_fc1   = (const float*)d_in[6];
    const float* b_fc1   = (const float*)d_in[7];
    const float* w_conv2 = (const float*)d_in[8];
    const float* b_conv2 = (const float*)d_in[9];
    const float* w_fc2   = (const float*)d_in[10];
    const float* b_fc2   = (const float*)d_in[11];
    const float* w_conv3 = (const float*)d_in[12];
    const float* b_conv3 = (const float*)d_in[13];

    const int N = in_sizes[0] / 64;       // 50000
    const int E = in_sizes[1] / 2;        // 800000
    const int* row = ei;
    const int* col = ei + E;

    const int nb = (N + 255) / 256;       // 196 buckets
    const int nbc = (E + 2047) / 2048;    // 391 bucket-count blocks
    const int nblk = (N + 63) / 64;       // 782 (64-row blocks, fused GEMM)

    // workspace layout. alloc() takes 4-BYTE units (chunks padded to 16B).
    char* p = (char*)d_ws;
    auto alloc = [&](size_t elems) {
        void* q = p; p += ((elems + 3) & ~(size_t)3) * 4; return q;
    };
    int*    bcnt    = (int*)   alloc(200);   // adjacent to bcur: one memset
    int*    bcur    = (int*)   alloc(200);
    int*    rowptr  = (int*)   alloc(N + 4);
    uint*   stage   = (uint*)  alloc(E);                   // packed (col<<16|row)
    ushort* csr16   = (ushort*)alloc((size_t)E / 2);       // 2B row index per edge
    float*  dis     = (float*) alloc(N);
    ushort* xh      = (ushort*)alloc((size_t)N * 32);      // N*64 bf16
    ushort* xs      = (ushort*)alloc((size_t)N * 32);      // dis-scaled gather copy
    ushort* agghi   = (ushort*)alloc((size_t)N * 32);
    ushort* Bf      = (ushort*)alloc(65536);               // single bf16
    ushort* W0f     = (ushort*)alloc(16384);
    ushort* W1f     = (ushort*)alloc(16384);
    ushort* x5      = (ushort*)alloc((size_t)N * 64);      // N*128 bf16
    ushort* xw2     = (ushort*)alloc((size_t)N * 64);      // N*128 bf16
    float*  xw3     = (float*) alloc(N);

    float* out = (float*)d_out;

    // ---- CSR build + weight packing (bscan folded into binA/binB) ----
    hipMemsetAsync(bcnt, 0, 400 * sizeof(int), stream);    // bcnt + bcur
    k_setup<<<nbc + 96, 256, 0, stream>>>(col, bcnt, E, nbc,
                                          w_fc, w_conv1, w_fc1, w_conv2,
                                          W0f, W1f, Bf);
    k_binA<<<nbc, 256, 0, stream>>>(row, col, bcnt, bcur, stage, E);
    k_binB<<<nb, 256, 0, stream>>>(stage, bcnt, rowptr, dis, csr16,
                                   x, xh, xs, N, E);

    // conv1 propagate: agg = dis[col] * sum xs[row], wide-granule gather
    k_agg64_csr<<<(N + 3) / 4, 256, 0, stream>>>(xs, rowptr, csr16, dis, agghi, N);

    // fused: x1/x2 layers -> LDS x3 tile -> x5 = relu(x3@w_fc1+b), xw2 = dis*(x3@w_conv2)
    k_mmfused<<<nblk, 512, 0, stream>>>(xh, agghi, W0f, W1f, b_fc, b_conv1,
                                        Bf, b_fc1, dis, x5, xw2, N);

    // x7 in registers (wide-granule gather); fused dual dot -> out, xw3
    k_agg128_x7dot<<<(N + 3) / 4, 256, 0, stream>>>(
        xw2, rowptr, csr16, dis, b_conv2, x5,
        w_fc2, b_fc2, w_conv3, b_conv3, out, xw3, N);

    // out += dis[i] * sum xw3[row]
    k_agg1_csr<<<(N + 15) / 16, 256, 0, stream>>>(xw3, rowptr, csr16, dis, out, N);
}